// Round 6
// baseline (2055.420 us; speedup 1.0000x reference)
//
#include <hip/hip_runtime.h>

typedef _Float16 half8 __attribute__((ext_vector_type(8)));
typedef float f32x4 __attribute__((ext_vector_type(4)));
typedef unsigned long long u64;

#define MFMA16(a,b,c) __builtin_amdgcn_mfma_f32_16x16x32_f16((a),(b),(c),0,0,0)

constexpr int B_SZ = 128, S_LEN = 512, I_SZ = 512, H_SZ = 1024, O_SZ = 512;

// workspace layout (bytes)
constexpr size_t XW_OFF   = 0;                                            // f16 [S][B][H] (128 MB)
constexpr size_t X16_OFF  = XW_OFF   + (size_t)S_LEN * B_SZ * H_SZ * 2;   // f16 [B*S][I] (64 MB)
constexpr size_t WXHT_OFF = X16_OFF  + (size_t)B_SZ * S_LEN * I_SZ * 2;   // f16 [H][I]
constexpr size_t WHHT_OFF = WXHT_OFF + (size_t)H_SZ * I_SZ * 2;           // f16 [H][H]
constexpr size_t WYHT_OFF = WHHT_OFF + (size_t)H_SZ * I_SZ * 2 + (size_t)H_SZ * H_SZ * 2 - (size_t)H_SZ * I_SZ * 2; // = WHHT + H*H*2
constexpr size_t HB_OFF   = WYHT_OFF + (size_t)O_SZ * H_SZ * 2;           // u64 [8][2][16][256] (512 KB)
constexpr size_t TAG_OFF  = HB_OFF   + (size_t)8 * 2 * 16 * 1024 * 2;     // u32 [8][64]

// ---------------- agent-scope (L3 coherence point) helpers ----------------
__device__ __forceinline__ u64 ag_load64(const u64* p) {
  return __hip_atomic_load(p, __ATOMIC_RELAXED, __HIP_MEMORY_SCOPE_AGENT);
}
__device__ __forceinline__ unsigned ag_load32(const unsigned* p) {
  return __hip_atomic_load(p, __ATOMIC_RELAXED, __HIP_MEMORY_SCOPE_AGENT);
}
__device__ __forceinline__ void ag_store32(unsigned* p, unsigned v) {
  __hip_atomic_store(p, v, __ATOMIC_RELAXED, __HIP_MEMORY_SCOPE_AGENT);
}
// RMW publish: performed AT the coherence point -> vmcnt ack == globally visible.
__device__ __forceinline__ void ag_xchg64(u64* p, u64 v) {
  (void)__hip_atomic_exchange(p, v, __ATOMIC_RELAXED, __HIP_MEMORY_SCOPE_AGENT);
}

__device__ __forceinline__ float ftanh(float z) {
  // tanh(z) = 1 - 2/(e^{2z}+1); e^{2z} = 2^(2*log2e*z). Limits: +inf->1, -inf->-1.
  float e = __builtin_amdgcn_exp2f(z * 2.8853900817779268f);
  return fmaf(-2.f, __builtin_amdgcn_rcpf(e + 1.f), 1.f);
}

// ---------------- prep kernels (round-2 proven) ----------------
__global__ void k_cvt_x(const float* __restrict__ in, _Float16* __restrict__ out) {
  size_t i = ((size_t)blockIdx.x * 256 + threadIdx.x) * 8;
  float4 a = *(const float4*)(in + i);
  float4 b = *(const float4*)(in + i + 4);
  half8 h;
  h[0] = (_Float16)a.x; h[1] = (_Float16)a.y; h[2] = (_Float16)a.z; h[3] = (_Float16)a.w;
  h[4] = (_Float16)b.x; h[5] = (_Float16)b.y; h[6] = (_Float16)b.z; h[7] = (_Float16)b.w;
  *(half8*)(out + i) = h;
}

__global__ void k_transpose_cvt(const float* __restrict__ in, _Float16* __restrict__ out,
                                int K, int N) {
  int k = blockIdx.x * 256 + threadIdx.x;
  int n = blockIdx.y;
  out[(size_t)n * K + k] = (_Float16)in[(size_t)k * N + n];
}

// ---------------- phase 1: xW = x @ W_xh + b -> f16 [S][B][H] (round-2 proven) ----------------
__launch_bounds__(256, 1)
__global__ void k_xw_gemm(const _Float16* __restrict__ A,   // [65536][512]
                          const _Float16* __restrict__ BT,  // [1024][512]
                          const float* __restrict__ bias,   // [1024]
                          _Float16* __restrict__ xw)        // [S][B][H]
{
  const int m0 = blockIdx.y * 128;
  const int n0 = blockIdx.x * 128;
  __shared__ __align__(16) _Float16 la[128][72];
  __shared__ __align__(16) _Float16 lb[128][72];
  const int tid = threadIdx.x;
  const int w = tid >> 6, l = tid & 63;
  const int wr = w >> 1, wc = w & 1;
  const int cl = l & 15;
  const int kh = (l >> 4) << 3;
  const int rl = (l >> 4) << 2;

  f32x4 acc[4][4] = {};

  for (int kb = 0; kb < 512; kb += 64) {
    {
      const int r = tid >> 1, sg = tid & 1;
      const _Float16* ga = A  + (size_t)(m0 + r) * 512 + kb + sg * 32;
      const _Float16* gb = BT + (size_t)(n0 + r) * 512 + kb + sg * 32;
      _Float16* da = &la[r][sg * 32];
      _Float16* db = &lb[r][sg * 32];
      #pragma unroll
      for (int i = 0; i < 4; i++) *(half8*)(da + i * 8) = *(const half8*)(ga + i * 8);
      #pragma unroll
      for (int i = 0; i < 4; i++) *(half8*)(db + i * 8) = *(const half8*)(gb + i * 8);
    }
    __syncthreads();
    #pragma unroll
    for (int kk = 0; kk < 64; kk += 32) {
      half8 af[4], bf[4];
      #pragma unroll
      for (int mi = 0; mi < 4; mi++) af[mi] = *(const half8*)(&la[wr * 64 + mi * 16 + cl][kk + kh]);
      #pragma unroll
      for (int ni = 0; ni < 4; ni++) bf[ni] = *(const half8*)(&lb[wc * 64 + ni * 16 + cl][kk + kh]);
      #pragma unroll
      for (int mi = 0; mi < 4; mi++)
        #pragma unroll
        for (int ni = 0; ni < 4; ni++)
          acc[mi][ni] = MFMA16(af[mi], bf[ni], acc[mi][ni]);
    }
    __syncthreads();
  }

  #pragma unroll
  for (int mi = 0; mi < 4; mi++)
    #pragma unroll
    for (int ni = 0; ni < 4; ni++) {
      const int col = n0 + wc * 64 + ni * 16 + cl;
      const float bv = bias[col];
      #pragma unroll
      for (int r = 0; r < 4; r++) {
        const int m = m0 + wr * 64 + mi * 16 + rl + r;
        const int b = m >> 9;        // A rows are (b, s), S=512
        const int s = m & 511;
        xw[((size_t)(s * B_SZ + b) << 10) + col] = (_Float16)(acc[mi][ni][r] + bv);
      }
    }
}

// ---------------- phase 2+3: persistent recurrence ----------------
// 8 groups (g=bid&7, 16 batch rows) x 32 wgs (j=bid>>3, 32 H-cols), 2 waves/wg.
// Structure = round-2 PASSED kernel. Deltas vs round 2:
//  - per-(wg,wave) monotonic tags (64/group) replace the central fetch_add barrier
//  - h published via agent-scope RMW exchange: vmcnt ack => at coherence point,
//    so tag-after-drain is sound regardless of writeback ordering
//  - double-buffered lh + wave-local bounce => 1 __syncthreads per step
// Producer slot s=(j,w) publishes tag=t+1 only after its h_{t+1} RMWs are
// drained. Consumer polls all 64 tags >= t before reading h_t. Tag t from ALL
// producers also proves step t-1's reads finished => overwriting h_{t-1}'s
// parity buffer at step t is safe. Polls are bounded: bug => wrong answer, not hang.

__device__ __forceinline__ void poll_tags64(const unsigned* gtag, int l, unsigned t) {
  for (int it = 0; it < (1 << 17); ++it) {
    unsigned tg = ag_load32(gtag + l);
    if (__all((int)(tg >= t))) break;
    __builtin_amdgcn_s_sleep(1);
  }
  __builtin_amdgcn_sched_barrier(0);   // keep h loads below the poll
}

__launch_bounds__(128, 1)
__global__ void k_rnn(const _Float16* __restrict__ xw,
                      const _Float16* __restrict__ WhhT,   // [H][H]
                      const _Float16* __restrict__ WyhT,   // [O][H]
                      const float* __restrict__ Wby,
                      u64* __restrict__ hb,                // [8][2][16][256] u64
                      unsigned* __restrict__ tags,         // [8][64]
                      float* __restrict__ out)             // [B][O]
{
  __shared__ __align__(16) _Float16 lw[32][1032];     // W_hh^T slice
  __shared__ __align__(16) _Float16 lh[2][16][1032];  // h tile, double-buffered
  __shared__ __align__(16) _Float16 st[2][16][40];    // per-wave repack bounce

  const int bid = blockIdx.x;
  const int g = bid & 7, j = bid >> 3;
  const int tid = threadIdx.x;
  const int w = tid >> 6, l = tid & 63;
  const int cl = l & 15;
  const int kh = (l >> 4) << 3;
  const int rl = (l >> 4) << 2;
  const int r0 = g << 4;
  const int n0 = j << 5;
  const int colg = n0 + (w << 4) + cl;    // owned H column
  const int hr = tid >> 3, hs = tid & 7;  // staging: 16 rows x 8 lanes
  unsigned* gtag = tags + (g << 6);
  const int slot = (j << 1) + w;
  u64* hbg = hb + ((size_t)g << 13);      // 2*16*256 u64 per group

  { // load W_hh^T rows n0..n0+31 (once; round-2 pattern)
    const int rr = tid >> 2, sg = tid & 3;
    const _Float16* src = WhhT + ((size_t)(n0 + rr) << 10) + (sg << 8);
    _Float16* dst = &lw[rr][sg << 8];
    #pragma unroll
    for (int i = 0; i < 32; i++)
      *(half8*)(dst + (i << 3)) = *(const half8*)(src + (i << 3));
  }
  __syncthreads();

  for (int t = 0; t < 512; t++) {
    // xw_t addend (plain scalar loads; xw is constant; complete under poll/stage)
    float xv[4];
    {
      const _Float16* p = xw + ((size_t)(t * 128 + r0 + rl) << 10) + colg;
      #pragma unroll
      for (int r = 0; r < 4; r++) xv[r] = (float)p[(size_t)r << 10];
    }

    if (t > 0) {
      poll_tags64(gtag, l, (unsigned)t);
      // stage h_t -> lh[t&1] (round-2 proven pattern, group-local addresses)
      u64 a[32];
      const u64* hsrc = hbg + ((size_t)(t & 1) << 12) + (hr << 8) + (hs << 1);
      #pragma unroll
      for (int i = 0; i < 16; i++) {
        a[2 * i]     = ag_load64(hsrc + (i << 4));
        a[2 * i + 1] = ag_load64(hsrc + (i << 4) + 1);
      }
      _Float16* ld = &lh[t & 1][hr][hs << 3];
      #pragma unroll
      for (int i = 0; i < 16; i++) {
        *(u64*)(ld + (i << 6))     = a[2 * i];
        *(u64*)(ld + (i << 6) + 4) = a[2 * i + 1];
      }
    }
    __syncthreads();   // lh[t&1] ready; also separates lh buffers across waves

    f32x4 acc0 = {}, acc1 = {};
    if (t > 0) {
      const _Float16 (*lhb)[1032] = lh[t & 1];
      #pragma unroll 4
      for (int kc = 0; kc < 32; kc += 2) {   // two interleaved acc chains
        half8 a0 = *(const half8*)&lhb[cl][(kc << 5) + kh];
        half8 b0 = *(const half8*)&lw[(w << 4) + cl][(kc << 5) + kh];
        acc0 = MFMA16(a0, b0, acc0);
        half8 a1 = *(const half8*)&lhb[cl][((kc + 1) << 5) + kh];
        half8 b1 = *(const half8*)&lw[(w << 4) + cl][((kc + 1) << 5) + kh];
        acc1 = MFMA16(a1, b1, acc1);
      }
    }

    // h_{t+1} = tanh(xw_t + h_t @ W_hh): wave-local bounce, RMW publish
    #pragma unroll
    for (int r = 0; r < 4; r++) {
      float z = xv[r] + acc0[r] + acc1[r];
      st[w][rl + r][cl] = (_Float16)ftanh(z);
    }
    asm volatile("s_waitcnt lgkmcnt(0)" ::: "memory");  // wave-local LDS RAW
    __builtin_amdgcn_sched_barrier(0);
    {
      u64 pv = *(const u64*)&st[w][l >> 2][(l & 3) << 2];
      u64* dst = hbg + ((size_t)((t + 1) & 1) << 12) + ((size_t)(l >> 2) << 8)
               + (j << 3) + (w << 2) + (l & 3);
      ag_xchg64(dst, pv);
    }
    asm volatile("s_waitcnt vmcnt(0)" ::: "memory");    // h at coherence point
    if (l == 0) ag_store32(gtag + slot, (unsigned)(t + 1));
  }

  // ---------- phase 3: out = h_512 @ W_yh + b_y (h_512 in parity-0 buffer) ----------
  poll_tags64(gtag, l, 512u);
  { // stage h_512 -> lh[0]
    u64 a[32];
    const u64* hsrc = hbg + (hr << 8) + (hs << 1);
    #pragma unroll
    for (int i = 0; i < 16; i++) {
      a[2 * i]     = ag_load64(hsrc + (i << 4));
      a[2 * i + 1] = ag_load64(hsrc + (i << 4) + 1);
    }
    _Float16* ld = &lh[0][hr][hs << 3];
    #pragma unroll
    for (int i = 0; i < 16; i++) {
      *(u64*)(ld + (i << 6))     = a[2 * i];
      *(u64*)(ld + (i << 6) + 4) = a[2 * i + 1];
    }
  }
  __syncthreads();
  if (w == 0) {
    f32x4 a0 = {}, a1 = {};
    const int oc = (j << 4) + cl;     // 32 wgs x 16 cols = 512
    const _Float16* bsrc = WyhT + ((size_t)oc << 10);
    #pragma unroll 4
    for (int kc = 0; kc < 32; kc += 2) {
      half8 av  = *(const half8*)&lh[0][cl][(kc << 5) + kh];
      half8 bv  = *(const half8*)(bsrc + (kc << 5) + kh);
      a0 = MFMA16(av, bv, a0);
      half8 av1 = *(const half8*)&lh[0][cl][((kc + 1) << 5) + kh];
      half8 bv1 = *(const half8*)(bsrc + ((kc + 1) << 5) + kh);
      a1 = MFMA16(av1, bv1, a1);
    }
    const float bb = Wby[oc];
    #pragma unroll
    for (int r = 0; r < 4; r++)
      out[((size_t)(r0 + rl + r) << 9) + oc] = a0[r] + a1[r] + bb;
  }
}

// ---------------- host ----------------
extern "C" void kernel_launch(void* const* d_in, const int* in_sizes, int n_in,
                              void* d_out, int out_size, void* d_ws, size_t ws_size,
                              hipStream_t stream) {
  const float* x   = (const float*)d_in[0];
  const float* Wxh = (const float*)d_in[1];
  const float* Whh = (const float*)d_in[2];
  const float* Wyh = (const float*)d_in[3];
  const float* Wbh = (const float*)d_in[4];
  const float* Wby = (const float*)d_in[5];
  float* out = (float*)d_out;

  char* ws = (char*)d_ws;
  _Float16* xw   = (_Float16*)(ws + XW_OFF);
  _Float16* x16  = (_Float16*)(ws + X16_OFF);
  _Float16* WxhT = (_Float16*)(ws + WXHT_OFF);
  _Float16* WhhT = (_Float16*)(ws + WHHT_OFF);
  _Float16* WyhT = (_Float16*)(ws + WYHT_OFF);
  u64*      hb   = (u64*)(ws + HB_OFF);
  unsigned* tags = (unsigned*)(ws + TAG_OFF);

  hipMemsetAsync(tags, 0, 8 * 64 * sizeof(unsigned), stream);

  k_cvt_x<<<16384, 256, 0, stream>>>(x, x16);
  k_transpose_cvt<<<dim3(2, 1024), 256, 0, stream>>>(Wxh, WxhT, 512, 1024);
  k_transpose_cvt<<<dim3(4, 1024), 256, 0, stream>>>(Whh, WhhT, 1024, 1024);
  k_transpose_cvt<<<dim3(4, 512),  256, 0, stream>>>(Wyh, WyhT, 1024, 512);

  k_xw_gemm<<<dim3(8, 512), 256, 0, stream>>>(x16, WxhT, Wbh, xw);

  k_rnn<<<256, 128, 0, stream>>>(xw, WhhT, WyhT, Wby, hb, tags, out);
}